// Round 8
// baseline (219.191 us; speedup 1.0000x reference)
//
#include <hip/hip_runtime.h>

// x: [8, 1, 160, 160, 160] fp32; log_sigma: [3] fp32; out: scalar fp32.
// loss = -(sum over 3816 (axis,b,pair) of exp(-sq/(2*sigma_axis^2))) / 3816.
//
// R14: L3 WARM-UP PREFETCH. Budget now closes: 196 = fill(75, harness) +
// x-restore copy(~43, harness, the residual that made R11/R13 tail fixes
// null) + diff3(~70) + reduce(~3) + gaps(~5). diff3's 70us = 162MB cold
// (the 524MB poison sweep evicts x from L3 each iter) at ~2.4-2.7 TB/s.
// R7/R9/R11 proved diff3's own schedule can't improve the cold read; R10
// proved L3-WARM passes run 17.7us (~10 TB/s effective). Untested: pure
// LINEAR cold read BW in this context. This round splits cold-streaming
// from tiled consumption: warm_kernel (2048 blk x 256 thr, grid-stride
// float4, asm-sink keeps loads live) pulls all 131MB of x into Infinity
// Cache (reads allocate; x fits 256MB), then diff3 (R13 verbatim: R6 body
// + transposed coalesced ws) consumes L3-warm. warm_kernel's rocprof row
// = pure-linear-read BW measurement. Predictions: linear read ~6 TB/s ->
// warm ~22us, diff3 ~25us, total ~172-182. If warm also runs ~2.7 TB/s:
// total ~196-205 (cost-neutral) and cold-read ceiling is proven platform-
// wide -> roofline. absmax stays 0.0.

constexpr int Wd4 = 40;              // float4 per row
constexpr int SLICE4 = 6400;         // float4 per slice
constexpr long BSTR4 = 160L * 6400;  // float4 per batch
constexpr int NB = 8;
constexpr int NPAIR = 159;
constexpr int PBATCH = NB * NPAIR;     // 1272 keys per axis
constexpr int NKEY = 3 * PBATCH;       // 3816
constexpr int NBLK = NB * 160;         // 8 b x 32 d-segs x 5 h-chunks = 1280
constexpr int NRED = 60;               // 60*64 = 3840 >= 3816 keys
constexpr int HT_OFF = 5 * PBATCH;     // ws: Dt[5][1272] @0, Ht[32][1272], Wt[160][1272]
constexpr int WT_OFF = 37 * PBATCH;
constexpr long X4 = 8192000;           // float4 elements in x (131 MB)
constexpr int WARM_BLK = 2048;         // 8 blocks/CU, 32 waves/CU

__device__ __forceinline__ float sq4(const float4& a, const float4& c) {
    float e0 = a.x - c.x, e1 = a.y - c.y, e2 = a.z - c.z, e3 = a.w - c.w;
    return e0 * e0 + e1 * e1 + e2 * e2 + e3 * e3;
}

// Pure linear streaming read of x -> allocates x into Infinity Cache.
// Loads kept live via asm sink (no DCE); nothing written.
__global__ __launch_bounds__(256) void warm_kernel(const float4* __restrict__ x4) {
    const long stride = (long)WARM_BLK * 256;
    long i = (long)blockIdx.x * 256 + threadIdx.x;
    float a0 = 0.f, a1 = 0.f, a2 = 0.f, a3 = 0.f;
    // 15-16 iters/thread; unrolled x4 batches -> 4 independent loads in flight.
#pragma unroll 4
    for (; i < X4; i += stride) {
        const float4 v = x4[i];
        a0 += v.x; a1 += v.y; a2 += v.z; a3 += v.w;
    }
    asm volatile("" :: "v"(a0), "v"(a1), "v"(a2), "v"(a3));
}

// 1280 blocks x 320 threads. bid -> (b, ds 0..31, hc 0..4). Thread: c4=t%40,
// rp=t/40 owns rows h0+4rp+{0..3}. Slices d0..d0+4 owned, d0+5 halo (v only).
__global__ __launch_bounds__(320) void diff3_kernel(const float* __restrict__ x,
                                                    float* __restrict__ ws,
                                                    float* __restrict__ out) {
    __shared__ float lds[1504];  // H: [0..1311] 32 keys*41; D: [1472..1496]; W reuses [0..1439]

    const int t = threadIdx.x;
    const int bid = blockIdx.x;
    const int b = bid / 160;
    const int r2 = bid % 160;
    const int ds = r2 / 5;     // d-segment, d0 = 5*ds
    const int hc = r2 % 5;     // h-chunk,  h0 = 32*hc
    const int d0 = ds * 5, h0 = hc * 32;
    const bool lastSeg = (ds == 31);

    const int c4 = t % 40;
    const int rp = t / 40;                  // 0..7
    const int lane = t & 63;
    const int wv = t >> 6;                  // wave 0..4
    const bool hOK = !(hc == 4 && rp == 7); // row h0+4rp+4 <= 159
    const bool sOK = (c4 < 39);
    const bool fixB = (lane == 63) && sOK;  // shfl partner in next wave -> load

    if (bid == 0 && t == 0) out[0] = 0.f;   // reduce_kernel accumulates after us

    const float4* base = (const float4*)x + (size_t)b * BSTR4 + (size_t)d0 * SLICE4
                       + (size_t)(h0 + 4 * rp) * Wd4 + c4;

    float aW[4] = {0.f, 0.f, 0.f, 0.f};
    float aH[4] = {0.f, 0.f, 0.f, 0.f};
    float aD[5] = {0.f, 0.f, 0.f, 0.f, 0.f};
    float4 p0, p1, p2, p3;

#pragma unroll
    for (int it = 0; it < 5; ++it) {
        const float4* sp = base + it * SLICE4;
        const float4 v0 = sp[0];
        const float4 v1 = sp[Wd4];
        const float4 v2 = sp[2 * Wd4];
        const float4 v3 = sp[3 * Wd4];
        float4 hv;
        if (hOK) hv = sp[4 * Wd4];
        float bx0 = 0.f, bx1 = 0.f, bx2 = 0.f, bx3 = 0.f;
        if (fixB) {  // cross-wave w-boundary partner: scalar loads (4 thr/block)
            bx0 = ((const float*)(sp))[4];
            bx1 = ((const float*)(sp + Wd4))[4];
            bx2 = ((const float*)(sp + 2 * Wd4))[4];
            bx3 = ((const float*)(sp + 3 * Wd4))[4];
        }
        // w-boundary partner .x from lane+1 (same row, next float4)
        float s0 = __shfl_down(v0.x, 1, 64); if (fixB) s0 = bx0;
        float s1 = __shfl_down(v1.x, 1, 64); if (fixB) s1 = bx1;
        float s2 = __shfl_down(v2.x, 1, 64); if (fixB) s2 = bx2;
        float s3 = __shfl_down(v3.x, 1, 64); if (fixB) s3 = bx3;

        float dw;
        dw = v0.y - v0.x; aW[0] += dw * dw;
        dw = v0.z - v0.y; aW[1] += dw * dw;
        dw = v0.w - v0.z; aW[2] += dw * dw;
        dw = v1.y - v1.x; aW[0] += dw * dw;
        dw = v1.z - v1.y; aW[1] += dw * dw;
        dw = v1.w - v1.z; aW[2] += dw * dw;
        dw = v2.y - v2.x; aW[0] += dw * dw;
        dw = v2.z - v2.y; aW[1] += dw * dw;
        dw = v2.w - v2.z; aW[2] += dw * dw;
        dw = v3.y - v3.x; aW[0] += dw * dw;
        dw = v3.z - v3.y; aW[1] += dw * dw;
        dw = v3.w - v3.z; aW[2] += dw * dw;
        if (sOK) {
            dw = s0 - v0.w; aW[3] += dw * dw;
            dw = s1 - v1.w; aW[3] += dw * dw;
            dw = s2 - v2.w; aW[3] += dw * dw;
            dw = s3 - v3.w; aW[3] += dw * dw;
        }
        // h: 3 register-local pairs + 1 via hv
        aH[0] += sq4(v1, v0);
        aH[1] += sq4(v2, v1);
        aH[2] += sq4(v3, v2);
        if (hOK) aH[3] += sq4(hv, v3);
        // d: vs previous slice (rolling regs)
        if (it > 0)
            aD[it - 1] += sq4(v0, p0) + sq4(v1, p1) + sq4(v2, p2) + sq4(v3, p3);
        p0 = v0; p1 = v1; p2 = v2; p3 = v3;  // SSA under full unroll
    }
    if (!lastSeg) {  // halo slice d0+5: v-only, completes pair key d0+4
        const float4* sp = base + 5 * SLICE4;
        aD[4] = sq4(sp[0], p0) + sq4(sp[Wd4], p1) + sq4(sp[2 * Wd4], p2) + sq4(sp[3 * Wd4], p3);
    }

    // ---- flush (R6 LDS phases verbatim). Phase 1: H per-key scratch + D wave-reduce.
#pragma unroll
    for (int j = 0; j < 4; ++j) lds[(4 * rp + j) * 41 + c4] = aH[j];
#pragma unroll
    for (int j = 0; j < 5; ++j) {
        float dd = aD[j];
        for (int off = 32; off > 0; off >>= 1) dd += __shfl_down(dd, off, 64);
        if (lane == 0) lds[1472 + j * 5 + wv] = dd;
    }
    __syncthreads();
    float hsum = 0.f, dsum = 0.f;
    if (t < 32) {
        const float* src = &lds[t * 41];
        for (int i = 0; i < 40; ++i) hsum += src[i];
    }
    if (t < 5) {
        for (int w2 = 0; w2 < 5; ++w2) dsum += lds[1472 + t * 5 + w2];
    }
    __syncthreads();  // H region reads done; reuse for W
    // Phase 2: W per-key scratch (key 4c4+j, 8 contributors rp).
#pragma unroll
    for (int j = 0; j < 4; ++j) lds[(4 * c4 + j) * 9 + rp] = aW[j];
    __syncthreads();
    float wsum = 0.f;
    if (t < 160) {
        const float* src = &lds[t * 9];
        for (int i = 0; i < 8; ++i) wsum += src[i];
    }

    // ---- transposed, coalesced ws writes (R13). Every cell written once:
    const int kb = b * NPAIR;
    if (t < 5 && (d0 + t) < NPAIR)  ws[hc * PBATCH + kb + d0 + t] = dsum;
    if (t < 32 && (h0 + t) < NPAIR) ws[HT_OFF + ds * PBATCH + kb + h0 + t] = hsum;
    if (t < NPAIR)                  ws[WT_OFF + r2 * PBATCH + kb + t] = wsum;
}

// 60 blocks x 64 threads: one thread per (axis,b,pair). Contributor-major
// layout -> 256B contiguous per wave-iteration. Summation order per key
// identical to R6. final fused: one atomicAdd per block into out.
__global__ __launch_bounds__(64) void reduce_kernel(const float* __restrict__ ws,
                                                    const float* __restrict__ log_sigma,
                                                    float* __restrict__ out) {
    const int gk = blockIdx.x * 64 + threadIdx.x;
    float kv = 0.f;
    if (gk < NKEY) {
        const int a = gk / PBATCH;
        const int rem = gk % PBATCH;   // b*159 + pair
        const float f = -0.5f * expf(-2.f * log_sigma[a]);  // -1/(2*sigma^2)
        float val = 0.f;
        if (a == 0) {
            for (int hc = 0; hc < 5; ++hc)   val += ws[hc * PBATCH + rem];
        } else if (a == 1) {
            for (int dss = 0; dss < 32; ++dss) val += ws[HT_OFF + dss * PBATCH + rem];
        } else {
            for (int ci = 0; ci < 160; ++ci) val += ws[WT_OFF + ci * PBATCH + rem];
        }
        kv = expf(val * f);
    }
    for (int off = 32; off > 0; off >>= 1) kv += __shfl_down(kv, off, 64);
    if (threadIdx.x == 0) atomicAdd(out, -kv / (float)NKEY);
}

extern "C" void kernel_launch(void* const* d_in, const int* in_sizes, int n_in,
                              void* d_out, int out_size, void* d_ws, size_t ws_size,
                              hipStream_t stream) {
    const float* x = (const float*)d_in[0];
    const float* log_sigma = (const float*)d_in[1];
    float* out = (float*)d_out;
    float* ws = (float*)d_ws;

    warm_kernel<<<WARM_BLK, 256, 0, stream>>>((const float4*)x);
    diff3_kernel<<<NBLK, 320, 0, stream>>>(x, ws, out);
    reduce_kernel<<<NRED, 64, 0, stream>>>(ws, log_sigma, out);
}